// Round 9
// baseline (308.915 us; speedup 1.0000x reference)
//
#include <hip/hip_runtime.h>
#include <math.h>

#define N_NODES 100000
#define N_EDGES 1000000
#define IN_DIM  128
#define OUT_DIM 64
#define NEG     0.2f

#define SCAN_BLOCKS 391   // ceil(100000/256)
#define EDGE_BLOCKS 3907  // ceil(1000000/256): one edge per thread
#define K1_BLOCKS   782   // ceil(100000/128): 128-node tiles

// ---------------------------------------------------------------------------
// K1: Wh = h @ W^T + b, s_src = Wh.a1, s_tgt = Wh.a2.
// R8 was LDS-return-BW bound: 16 W-broadcast b128/iter/wave at ~12cyc each
// (RF write is 1KB regardless of broadcast), model 160k cyc/CU = 66us ~ meas.
// Fix: 128-node tile, TWO nodes per lane (accA/accB) -> W read once per tile
// instead of twice. DS model: 3.05 tiles/CU x 4 waves x 576 reads x 12cyc
// ~ 84k cyc = 35us. LDS ~105KB -> 1 block/CU (fine: DS pipe is the limiter,
// not occupancy). Pure-DS inner loop (R4: never mix s_load with ds_read).
// ---------------------------------------------------------------------------
__global__ __launch_bounds__(256, 1) void k1_gemm(
    const float* __restrict__ h, const float* __restrict__ W,
    const float* __restrict__ Wb, const float* __restrict__ aw,
    float* __restrict__ Wh, float* __restrict__ s_src, float* __restrict__ s_tgt)
{
    __shared__ float4 hts[128 * 33];  // 67.6 KB; aliased as tr[128][68] floats
    __shared__ float4 wts[64 * 32];   // 32 KB: wts[d*32 + k4] = W[d][4k4..]
    __shared__ float  sp1[4][128];    // per-wave p1 partials
    __shared__ float  sp2[4][128];    // per-wave p2 partials

    const int tid = threadIdx.x;
    const int n0 = blockIdx.x * 128;

    // stage W: 2048 float4, coalesced global, stride-1 LDS writes
    {
        const float4* W4 = (const float4*)W;
#pragma unroll
        for (int it = 0; it < 8; ++it) {
            int i = tid + 256 * it;
            wts[i] = W4[i];
        }
    }
    // stage h: 128 rows x 32 float4, row stride 33 (conflict-free b128 later)
    {
        const float4* h4 = (const float4*)h;
#pragma unroll
        for (int it = 0; it < 16; ++it) {
            int i = tid + 256 * it;            // 0..4095
            int n = i >> 5, k4 = i & 31;
            float4 v = make_float4(0.f, 0.f, 0.f, 0.f);
            if (n0 + n < N_NODES) v = h4[(size_t)(n0 + n) * 32 + k4];
            hts[n * 33 + k4] = v;
        }
    }
    __syncthreads();

    const int lane = tid & 63;
    const int w = tid >> 6;             // 0..3
    const int d0 = w * 16;
    const float4* hrowA = &hts[lane * 33];          // node n0+lane
    const float4* hrowB = &hts[(64 + lane) * 33];   // node n0+64+lane

    float accA[16], accB[16];
#pragma unroll
    for (int dd = 0; dd < 16; ++dd) { accA[dd] = 0.f; accB[dd] = 0.f; }

#pragma unroll 2
    for (int k4 = 0; k4 < 32; ++k4) {
        float4 ha = hrowA[k4];
        float4 hb = hrowB[k4];
#pragma unroll
        for (int dd = 0; dd < 16; ++dd) {
            float4 wv = wts[(d0 + dd) * 32 + k4];   // uniform addr -> broadcast
            accA[dd] = fmaf(wv.x, ha.x, accA[dd]);
            accA[dd] = fmaf(wv.y, ha.y, accA[dd]);
            accA[dd] = fmaf(wv.z, ha.z, accA[dd]);
            accA[dd] = fmaf(wv.w, ha.w, accA[dd]);
            accB[dd] = fmaf(wv.x, hb.x, accB[dd]);
            accB[dd] = fmaf(wv.y, hb.y, accB[dd]);
            accB[dd] = fmaf(wv.z, hb.z, accB[dd]);
            accB[dd] = fmaf(wv.w, hb.w, accB[dd]);
        }
    }

    // bias + score partials (each lane: nodes lane and 64+lane, 16 dims)
    float p1A = 0.f, p2A = 0.f, p1B = 0.f, p2B = 0.f;
#pragma unroll
    for (int dd = 0; dd < 16; ++dd) {
        float bd = Wb[d0 + dd];
        float a1 = aw[d0 + dd], a2 = aw[OUT_DIM + d0 + dd];
        float va = accA[dd] + bd;
        float vb = accB[dd] + bd;
        accA[dd] = va; accB[dd] = vb;
        p1A = fmaf(va, a1, p1A); p2A = fmaf(va, a2, p2A);
        p1B = fmaf(vb, a1, p1B); p2B = fmaf(vb, a2, p2B);
    }
    sp1[w][lane] = p1A;      sp2[w][lane] = p2A;
    sp1[w][64 + lane] = p1B; sp2[w][64 + lane] = p2B;
    __syncthreads();                   // hts reads done; safe to alias below

    // transpose Wh tile through LDS (row stride 68 floats)
    float* tr = (float*)hts;
#pragma unroll
    for (int dd = 0; dd < 16; ++dd) {
        tr[lane * 68 + d0 + dd] = accA[dd];
        tr[(64 + lane) * 68 + d0 + dd] = accB[dd];
    }
    __syncthreads();

    // coalesced Wh store: 2048 float4, 8 per thread
#pragma unroll
    for (int j = 0; j < 8; ++j) {
        int g = tid + 256 * j;         // 0..2047
        int n = g >> 4, d4 = g & 15;
        if (n0 + n < N_NODES) {
            float4 v = *(const float4*)&tr[n * 68 + d4 * 4];
            ((float4*)Wh)[(size_t)(n0 + n) * 16 + d4] = v;
        }
    }
    // score stores (coalesced): threads 0-127 -> s_src, 128-255 -> s_tgt
    if (tid < 128) {
        int n = n0 + tid;
        if (n < N_NODES)
            s_src[n] = sp1[0][tid] + sp1[1][tid] + sp1[2][tid] + sp1[3][tid];
    } else {
        int i = tid - 128;
        int n = n0 + i;
        if (n < N_NODES)
            s_tgt[n] = sp2[0][i] + sp2[1][i] + sp2[2][i] + sp2[3][i];
    }
}

// ---------------------------------------------------------------------------
// K2 (fused): one edge pass: deg histogram (capturing the returned RANK =
// CSR slot), ex = exp(leaky(l)) stored linearly, block-partial sums to
// bsum[] (plain store — single-address atomicAdd(gsum) serialized: R7).
// No max-subtraction: logits bounded (~|12|), exp can't overflow fp32,
// softmax is shift-invariant.
// ---------------------------------------------------------------------------
__global__ __launch_bounds__(256) void k2_fused(
    const int* __restrict__ ei, const float* __restrict__ s_src,
    const float* __restrict__ s_tgt, const float* __restrict__ ab,
    unsigned* __restrict__ deg, unsigned* __restrict__ rank,
    float* __restrict__ exv, float* __restrict__ bsum)
{
    const float ab0 = ab[0];
    float lsum = 0.f;
    const int e = blockIdx.x * blockDim.x + threadIdx.x;
    if (e < N_EDGES) {
        int s = ei[e], t = ei[N_EDGES + e];
        float x = s_src[s] + s_tgt[t] + ab0;
        float l = x > 0.f ? x : NEG * x;
        float ex = __expf(l);
        exv[e] = ex;
        lsum = ex;
        rank[e] = atomicAdd(&deg[t], 1u);   // returned old count = CSR rank
    }
#pragma unroll
    for (int off = 32; off; off >>= 1) lsum += __shfl_xor(lsum, off);
    __shared__ float ssum[4];
    if ((threadIdx.x & 63) == 0) ssum[threadIdx.x >> 6] = lsum;
    __syncthreads();
    if (threadIdx.x == 0)
        bsum[blockIdx.x] = ssum[0] + ssum[1] + ssum[2] + ssum[3];
}

// ---------------------------------------------------------------------------
// Scan (3 kernels): exclusive prefix sum of deg[100000] -> row[].
// k_scan2 additionally reduces bsum[] -> gsum.
// ---------------------------------------------------------------------------
__global__ __launch_bounds__(256) void k_scan1(
    const unsigned* __restrict__ deg, unsigned* __restrict__ psum)
{
    const int i = blockIdx.x * 256 + threadIdx.x;
    unsigned v = (i < N_NODES) ? deg[i] : 0u;
    unsigned w = v;
#pragma unroll
    for (int off = 32; off; off >>= 1) w += __shfl_xor(w, off);
    __shared__ unsigned ss[4];
    if ((threadIdx.x & 63) == 0) ss[threadIdx.x >> 6] = w;
    __syncthreads();
    if (threadIdx.x == 0) psum[blockIdx.x] = ss[0] + ss[1] + ss[2] + ss[3];
}

__global__ __launch_bounds__(512) void k_scan2(
    const unsigned* __restrict__ psum, unsigned* __restrict__ poff,
    const float* __restrict__ bsum, float* __restrict__ gsum)
{
    __shared__ unsigned sc[512];
    __shared__ float    sf[8];
    const int t = threadIdx.x;

    // part 1: exclusive scan of psum[SCAN_BLOCKS]
    unsigned v = (t < SCAN_BLOCKS) ? psum[t] : 0u;
    sc[t] = v;
    __syncthreads();
    for (int off = 1; off < 512; off <<= 1) {
        unsigned u = (t >= off) ? sc[t - off] : 0u;
        __syncthreads();
        sc[t] += u;
        __syncthreads();
    }
    if (t < SCAN_BLOCKS) poff[t] = sc[t] - v;   // exclusive

    // part 2: reduce bsum[EDGE_BLOCKS] -> gsum
    float s = 0.f;
    for (int i = t; i < EDGE_BLOCKS; i += 512) s += bsum[i];
#pragma unroll
    for (int off = 32; off; off >>= 1) s += __shfl_xor(s, off);
    if ((t & 63) == 0) sf[t >> 6] = s;
    __syncthreads();
    if (t == 0) {
        float tot = 0.f;
#pragma unroll
        for (int i = 0; i < 8; ++i) tot += sf[i];
        gsum[0] = tot;
    }
}

__global__ __launch_bounds__(256) void k_scan3(
    const unsigned* __restrict__ deg, const unsigned* __restrict__ poff,
    unsigned* __restrict__ row)
{
    __shared__ unsigned sc[256];
    const int t = threadIdx.x;
    const int i = blockIdx.x * 256 + t;
    unsigned v = (i < N_NODES) ? deg[i] : 0u;
    sc[t] = v;
    __syncthreads();
    for (int off = 1; off < 256; off <<= 1) {
        unsigned u = (t >= off) ? sc[t - off] : 0u;
        __syncthreads();
        sc[t] += u;
        __syncthreads();
    }
    unsigned r = poff[blockIdx.x] + sc[t] - v;   // exclusive
    if (i < N_NODES) row[i] = r;
    if (i == 0) row[N_NODES] = N_EDGES;
}

// ---------------------------------------------------------------------------
// K3: bin fill, NO atomics: pos = row[t] + rank[e]; scatter write is
// fire-and-forget. One edge per thread.
// ---------------------------------------------------------------------------
__global__ __launch_bounds__(256) void k3_fill(
    const int* __restrict__ ei, const float* __restrict__ exv,
    const unsigned* __restrict__ rank, const unsigned* __restrict__ row,
    int2* __restrict__ bin)
{
    const int e = blockIdx.x * blockDim.x + threadIdx.x;
    if (e >= N_EDGES) return;
    int t = ei[N_EDGES + e];
    unsigned pos = row[t] + rank[e];
    bin[pos] = make_int2(ei[e], __float_as_int(exv[e]));
}

// ---------------------------------------------------------------------------
// K4: gather — wave per tgt node, lane = dim. Bin chunk loaded coalesced
// (8B/lane), entries broadcast via shfl. 4-way ILP: 4 independent gathers +
// 4 accumulators per step. One plain store per node, leaky fused, no atomics.
// ---------------------------------------------------------------------------
__global__ __launch_bounds__(256) void k_gather(
    const unsigned* __restrict__ row, const int2* __restrict__ bin,
    const float* __restrict__ gsum, const float* __restrict__ Wh,
    float* __restrict__ out)
{
    const int lane = threadIdx.x & 63;
    const int t = blockIdx.x * 4 + (threadIdx.x >> 6);
    if (t >= N_NODES) return;
    const unsigned beg = row[t], end = row[t + 1];
    float a0 = 0.f, a1 = 0.f, a2 = 0.f, a3 = 0.f;
    for (unsigned base = beg; base < end; base += 64) {
        const int cnt = (int)min(64u, end - base);
        int2 p = make_int2(0, 0);
        if (lane < cnt) p = bin[base + lane];      // coalesced 8B/lane
        int j = 0;
        for (; j + 4 <= cnt; j += 4) {
            int   s0 = __shfl(p.x, j);     float w0 = __int_as_float(__shfl(p.y, j));
            int   s1 = __shfl(p.x, j + 1); float w1 = __int_as_float(__shfl(p.y, j + 1));
            int   s2 = __shfl(p.x, j + 2); float w2 = __int_as_float(__shfl(p.y, j + 2));
            int   s3 = __shfl(p.x, j + 3); float w3 = __int_as_float(__shfl(p.y, j + 3));
            float v0 = Wh[(size_t)s0 * OUT_DIM + lane];
            float v1 = Wh[(size_t)s1 * OUT_DIM + lane];
            float v2 = Wh[(size_t)s2 * OUT_DIM + lane];
            float v3 = Wh[(size_t)s3 * OUT_DIM + lane];
            a0 = fmaf(w0, v0, a0);
            a1 = fmaf(w1, v1, a1);
            a2 = fmaf(w2, v2, a2);
            a3 = fmaf(w3, v3, a3);
        }
        for (; j < cnt; ++j) {
            int   s = __shfl(p.x, j);
            float w = __int_as_float(__shfl(p.y, j));
            a0 = fmaf(w, Wh[(size_t)s * OUT_DIM + lane], a0);
        }
    }
    float v = ((a0 + a1) + (a2 + a3)) * (1.0f / gsum[0]);
    out[(size_t)t * OUT_DIM + lane] = v > 0.f ? v : NEG * v;
}

extern "C" void kernel_launch(void* const* d_in, const int* in_sizes, int n_in,
                              void* d_out, int out_size, void* d_ws, size_t ws_size,
                              hipStream_t stream)
{
    const float* h  = (const float*)d_in[0];
    const float* W  = (const float*)d_in[1];
    const float* Wb = (const float*)d_in[2];
    const float* aw = (const float*)d_in[3];
    const float* ab = (const float*)d_in[4];
    const int*   ei = (const int*)d_in[5];

    // ws layout: Wh[N*64] f32 | s_src[N] | s_tgt[N] | deg[N] u32 | row[N+1] u32
    //          | psum[512] | poff[512] | bin[E] int2 | exv[E] f32
    //          | rank[E] u32 | bsum[4096] f32 | gsum f32
    float* ws      = (float*)d_ws;
    float* Wh      = ws;
    float* s_src   = Wh + (size_t)N_NODES * OUT_DIM;
    float* s_tgt   = s_src + N_NODES;
    unsigned* deg    = (unsigned*)(s_tgt + N_NODES);
    unsigned* row    = deg + N_NODES;
    unsigned* psum   = row + N_NODES + 1;
    unsigned* poff   = psum + 512;
    int2*     bin    = (int2*)(poff + 512);
    float*    exv    = (float*)(bin + N_EDGES);
    unsigned* rank   = (unsigned*)(exv + N_EDGES);
    float*    bsum   = (float*)(rank + N_EDGES);
    float*    gsum   = bsum + 4096;

    float* out = (float*)d_out;

    hipMemsetAsync((void*)deg, 0, N_NODES * sizeof(unsigned), stream);

    k1_gemm<<<K1_BLOCKS, 256, 0, stream>>>(h, W, Wb, aw, Wh, s_src, s_tgt);
    k2_fused<<<EDGE_BLOCKS, 256, 0, stream>>>(ei, s_src, s_tgt, ab, deg, rank,
                                              exv, bsum);
    k_scan1<<<SCAN_BLOCKS, 256, 0, stream>>>(deg, psum);
    k_scan2<<<1, 512, 0, stream>>>(psum, poff, bsum, gsum);
    k_scan3<<<SCAN_BLOCKS, 256, 0, stream>>>(deg, poff, row);
    k3_fill<<<EDGE_BLOCKS, 256, 0, stream>>>(ei, exv, rank, row, bin);
    k_gather<<<(N_NODES + 3) / 4, 256, 0, stream>>>(row, bin, gsum, Wh, out);
}